// Round 1
// baseline (1143.451 us; speedup 1.0000x reference)
//
#include <hip/hip_runtime.h>
#include <math.h>

#define NODES   131072
#define EDGES   1048576
#define FDIM    32
#define HDIM    128
#define NGRAPH  512

// ---------------------------------------------------------------- k1: h0 = X @ W_in
// 128 threads per node (thread = output column). X row (128B) broadcast-read via L1,
// W_in (16KB) stays L1-resident across the grid-stride loop.
__global__ __launch_bounds__(256) void k1_proj(const float* __restrict__ x,
                                               const float* __restrict__ Win,
                                               float* __restrict__ h0, int N) {
    int t = threadIdx.x;
    int col = t & (HDIM - 1);
    int group0 = (int)((blockIdx.x * (size_t)blockDim.x + t) >> 7);
    int stride = (int)((gridDim.x * (size_t)blockDim.x) >> 7);
    for (int n = group0; n < N; n += stride) {
        const float* xr = x + (size_t)n * FDIM;
        float s = 0.f;
#pragma unroll
        for (int f = 0; f < FDIM; ++f)
            s = fmaf(xr[f], Win[f * HDIM + col], s);
        h0[(size_t)n * HDIM + col] = s;
    }
}

// ---------------------------------------------------------------- k2: msg[tgt] += h0[src] * w
// One wave (64 lanes) per edge; lane handles 2 consecutive floats (float2 gather,
// coalesced 512B per row), then 2 global f32 atomics.
__global__ __launch_bounds__(256) void k2_scatter(const float* __restrict__ h0,
                                                  const int* __restrict__ ei,
                                                  const float* __restrict__ ew,
                                                  float* __restrict__ msg, int E) {
    long long gid = blockIdx.x * (long long)blockDim.x + threadIdx.x;
    int e = (int)(gid >> 6);
    if (e >= E) return;
    int l = (int)(gid & 63);
    int src = ei[e];
    int tgt = ei[E + e];
    float w = ew[e];
    const float2 v = ((const float2*)(h0 + (size_t)src * HDIM))[l];
    float* dst = msg + (size_t)tgt * HDIM + 2 * l;
    atomicAdd(dst + 0, v.x * w);
    atomicAdd(dst + 1, v.y * w);
}

// ---------------------------------------------------------------- k3: h = relu(h0 + msg@W_msg); per-graph mean
// Block per graph (batch is sorted -> binary-search the node range).
// Thread t: column = t&127, half = t>>7 (which of 2 nodes processed per iter).
// W_msg column held in 128 VGPRs (fixed per thread, reused across all nodes).
// msg row staged in LDS, consumed as broadcast float4.
__global__ __launch_bounds__(256) void k3_msg_relu_pool(const float* __restrict__ h0,
                                                        const float* __restrict__ msg,
                                                        const float* __restrict__ Wmsg,
                                                        const int* __restrict__ batch,
                                                        float* __restrict__ gmean, int N) {
    int g = blockIdx.x;
    int t = threadIdx.x;
    int col = t & (HDIM - 1);
    int half = t >> 7;

    // lower_bound(batch, g) and lower_bound(batch, g+1)
    int lo = 0, hi = N;
    while (lo < hi) { int m = (lo + hi) >> 1; if (batch[m] < g) lo = m + 1; else hi = m; }
    int start = lo;
    hi = N;
    while (lo < hi) { int m = (lo + hi) >> 1; if (batch[m] < g + 1) lo = m + 1; else hi = m; }
    int end = lo;

    float wc[HDIM];
#pragma unroll
    for (int k = 0; k < HDIM; ++k) wc[k] = Wmsg[k * HDIM + col];

    __shared__ __align__(16) float mrow[2][HDIM];
    __shared__ float red[HDIM];

    float accp = 0.f;
    for (int n0 = start; n0 < end; n0 += 2) {
        int nn = n0 + half;
        if (nn < end) mrow[half][col] = msg[(size_t)nn * HDIM + col];
        __syncthreads();
        if (nn < end) {
            const float4* m4 = (const float4*)mrow[half];
            float a0 = 0.f, a1 = 0.f, a2 = 0.f, a3 = 0.f;
#pragma unroll
            for (int q = 0; q < HDIM / 4; ++q) {
                float4 mv = m4[q];
                a0 = fmaf(mv.x, wc[4 * q + 0], a0);
                a1 = fmaf(mv.y, wc[4 * q + 1], a1);
                a2 = fmaf(mv.z, wc[4 * q + 2], a2);
                a3 = fmaf(mv.w, wc[4 * q + 3], a3);
            }
            float hv = h0[(size_t)nn * HDIM + col] + ((a0 + a1) + (a2 + a3));
            accp += fmaxf(hv, 0.f);
        }
        __syncthreads();
    }

    if (half == 0) red[col] = accp;
    __syncthreads();
    if (half == 1) red[col] += accp;   // unique col per thread in this half -> no race
    __syncthreads();
    if (t < HDIM) {
        int cnt = end - start;
        gmean[(size_t)g * HDIM + t] = (cnt > 0) ? red[t] / (float)cnt : 0.f;
    }
}

// ---------------------------------------------------------------- k4: backbone + heads
// ge = [g,g] => s1 = relu(g @ (W1_top + W1_bot)); s2 = relu(s1@W2); then 4 logit heads + value.
__global__ __launch_bounds__(256) void k4_heads(const float* __restrict__ gmean,
                                                const float* __restrict__ W1,
                                                const float* __restrict__ W2,
                                                const float* __restrict__ Wa,
                                                const float* __restrict__ Ws,
                                                const float* __restrict__ Wt,
                                                const float* __restrict__ Wact,
                                                const float* __restrict__ Wv1,
                                                const float* __restrict__ Wv2,
                                                float* __restrict__ out) {
    int g = blockIdx.x;
    int t = threadIdx.x;
    __shared__ float gv[HDIM];
    __shared__ float s1[HDIM];
    __shared__ float s2v[64];
    __shared__ float v1[32];

    if (t < HDIM) gv[t] = gmean[(size_t)g * HDIM + t];
    __syncthreads();

    if (t < HDIM) {
        float s = 0.f;
#pragma unroll 8
        for (int k = 0; k < HDIM; ++k)
            s = fmaf(gv[k], W1[k * HDIM + t] + W1[(k + HDIM) * HDIM + t], s);
        s1[t] = fmaxf(s, 0.f);
    }
    __syncthreads();

    if (t < 64) {
        float s = 0.f;
#pragma unroll 8
        for (int k = 0; k < HDIM; ++k)
            s = fmaf(s1[k], W2[k * 64 + t], s);
        s2v[t] = fmaxf(s, 0.f);
    }
    __syncthreads();

    // logit heads: [Wa(5) | Ws(1000) | Wt(1000) | Wact(4)] = 2009 columns
    for (int c = t; c < 2009; c += 256) {
        const float* W; int colc, ncol; size_t oidx;
        if (c < 5)        { W = Wa;   colc = c;        ncol = 5;    oidx = (size_t)g * 5 + colc; }
        else if (c < 1005){ W = Ws;   colc = c - 5;    ncol = 1000; oidx = 2560 + (size_t)g * 1000 + colc; }
        else if (c < 2005){ W = Wt;   colc = c - 1005; ncol = 1000; oidx = 514560 + (size_t)g * 1000 + colc; }
        else              { W = Wact; colc = c - 2005; ncol = 4;    oidx = 1026560 + (size_t)g * 4 + colc; }
        float acc = 0.f;
#pragma unroll 8
        for (int k = 0; k < 64; ++k)
            acc = fmaf(s2v[k], W[k * ncol + colc], acc);
        out[oidx] = acc;
    }

    // value = tanh(relu(s2 @ Wv1) @ Wv2)
    if (t < 32) {
        float s = 0.f;
#pragma unroll 8
        for (int k = 0; k < 64; ++k)
            s = fmaf(s2v[k], Wv1[k * 32 + t], s);
        v1[t] = fmaxf(s, 0.f);
    }
    __syncthreads();
    if (t == 0) {
        float s = 0.f;
#pragma unroll
        for (int k = 0; k < 32; ++k)
            s = fmaf(v1[k], Wv2[k], s);
        out[1028608 + (size_t)g] = tanhf(s);
    }
}

// ----------------------------------------------------------------
extern "C" void kernel_launch(void* const* d_in, const int* in_sizes, int n_in,
                              void* d_out, int out_size, void* d_ws, size_t ws_size,
                              hipStream_t stream) {
    const float* x     = (const float*)d_in[0];
    const int*   ei    = (const int*)d_in[1];
    const float* ew    = (const float*)d_in[2];
    // d_in[3] = layer_positions (unused by reference)
    const int*   batch = (const int*)d_in[4];
    // d_in[5] = num_graphs scalar (fixed = 512)
    const float* Win   = (const float*)d_in[6];
    const float* Wmsg  = (const float*)d_in[7];
    const float* W1    = (const float*)d_in[8];
    const float* W2    = (const float*)d_in[9];
    const float* Wa    = (const float*)d_in[10];
    const float* Ws    = (const float*)d_in[11];
    const float* Wt    = (const float*)d_in[12];
    const float* Wact  = (const float*)d_in[13];
    const float* Wv1   = (const float*)d_in[14];
    const float* Wv2   = (const float*)d_in[15];
    float* out = (float*)d_out;

    char* ws = (char*)d_ws;
    const size_t nh_bytes = (size_t)NODES * HDIM * sizeof(float);  // 64 MB
    float* h0    = (float*)(ws);
    float* msg   = (float*)(ws + nh_bytes);
    float* gmean = (float*)(ws + 2 * nh_bytes);

    hipMemsetAsync(msg, 0, nh_bytes, stream);

    k1_proj<<<2048, 256, 0, stream>>>(x, Win, h0, NODES);

    int k2_blocks = (int)(((long long)EDGES * 64) / 256);
    k2_scatter<<<k2_blocks, 256, 0, stream>>>(h0, ei, ew, msg, EDGES);

    k3_msg_relu_pool<<<NGRAPH, 256, 0, stream>>>(h0, msg, Wmsg, batch, gmean, NODES);

    k4_heads<<<NGRAPH, 256, 0, stream>>>(gmean, W1, W2, Wa, Ws, Wt, Wact, Wv1, Wv2, out);
}

// Round 2
// 483.176 us; speedup vs baseline: 2.3665x; 2.3665x over previous
//
#include <hip/hip_runtime.h>
#include <math.h>

#define NODES   131072
#define EDGES   1048576
#define FDIM    32
#define HDIM    128
#define NGRAPH  512

// ---------------------------------------------------------------- k1: h0 = X @ W_in
__global__ __launch_bounds__(256) void k1_proj(const float* __restrict__ x,
                                               const float* __restrict__ Win,
                                               float* __restrict__ h0, int N) {
    int t = threadIdx.x;
    int col = t & (HDIM - 1);
    int group0 = (int)((blockIdx.x * (size_t)blockDim.x + t) >> 7);
    int stride = (int)((gridDim.x * (size_t)blockDim.x) >> 7);
    for (int n = group0; n < N; n += stride) {
        const float* xr = x + (size_t)n * FDIM;
        float s = 0.f;
#pragma unroll
        for (int f = 0; f < FDIM; ++f)
            s = fmaf(xr[f], Win[f * HDIM + col], s);
        h0[(size_t)n * HDIM + col] = s;
    }
}

// ---------------------------------------------------------------- CSR build (counting sort by target)
__global__ __launch_bounds__(256) void kh_hist(const int* __restrict__ ei,
                                               int* __restrict__ count, int E) {
    int e = blockIdx.x * blockDim.x + threadIdx.x;
    if (e < E) atomicAdd(&count[ei[E + e]], 1);
}

// exclusive scan of 131072 ints: 256 blocks x 512 elements
__global__ __launch_bounds__(256) void kh_scanA(const int* __restrict__ count,
                                                int* __restrict__ offs,
                                                int* __restrict__ blockSums) {
    int b = blockIdx.x, t = threadIdx.x;
    int base = b * 512 + 2 * t;
    int a0 = count[base], a1 = count[base + 1];
    int pair = a0 + a1;
    __shared__ int sh[256];
    sh[t] = pair;
    __syncthreads();
    for (int off = 1; off < 256; off <<= 1) {
        int v = (t >= off) ? sh[t - off] : 0;
        __syncthreads();
        sh[t] += v;
        __syncthreads();
    }
    int excl = sh[t] - pair;
    offs[base] = excl;
    offs[base + 1] = excl + a0;
    if (t == 255) blockSums[b] = sh[255];
}

__global__ __launch_bounds__(256) void kh_scanB(const int* __restrict__ blockSums,
                                                int* __restrict__ blockBase) {
    int t = threadIdx.x;
    int v0 = blockSums[t];
    __shared__ int sh[256];
    sh[t] = v0;
    __syncthreads();
    for (int off = 1; off < 256; off <<= 1) {
        int v = (t >= off) ? sh[t - off] : 0;
        __syncthreads();
        sh[t] += v;
        __syncthreads();
    }
    blockBase[t] = sh[t] - v0;
}

__global__ __launch_bounds__(256) void kh_scanC(int* __restrict__ offs,
                                                int* __restrict__ cursor,
                                                const int* __restrict__ blockBase) {
    int b = blockIdx.x, t = threadIdx.x;
    int base = b * 512 + 2 * t;
    int add = blockBase[b];
    int o0 = offs[base] + add, o1 = offs[base + 1] + add;
    offs[base] = o0; offs[base + 1] = o1;
    cursor[base] = o0; cursor[base + 1] = o1;
}

// bucket[pos] = {src, bits(w)} ; after this, cursor[n] == offs[n+1]
__global__ __launch_bounds__(256) void kh_fill(const int* __restrict__ ei,
                                               const float* __restrict__ ew,
                                               int* __restrict__ cursor,
                                               int2* __restrict__ bucket, int E) {
    int e = blockIdx.x * blockDim.x + threadIdx.x;
    if (e >= E) return;
    int src = ei[e];
    int tgt = ei[E + e];
    float w = ew[e];
    int pos = atomicAdd(&cursor[tgt], 1);
    bucket[pos] = make_int2(src, __float_as_int(w));
}

// ---------------------------------------------------------------- gather: msg[n] = sum_in h0[src]*w
// One wave per target node; lane handles 2 consecutive floats (float2, coalesced 512B rows).
__global__ __launch_bounds__(256) void kg_gather(const float* __restrict__ h0,
                                                 const int* __restrict__ offs,
                                                 const int* __restrict__ cursor,
                                                 const int2* __restrict__ bucket,
                                                 float* __restrict__ msg, int N) {
    long long gid = blockIdx.x * (long long)blockDim.x + threadIdx.x;
    int n = (int)(gid >> 6);
    if (n >= N) return;
    int l = (int)(gid & 63);
    int beg = offs[n];
    int end = cursor[n];           // == offs[n+1] after kh_fill
    float2 acc = {0.f, 0.f};
    int j = beg;
    for (; j + 1 < end; j += 2) {
        int2 e0 = bucket[j];
        int2 e1 = bucket[j + 1];
        float w0 = __int_as_float(e0.y);
        float w1 = __int_as_float(e1.y);
        float2 v0 = ((const float2*)(h0 + (size_t)e0.x * HDIM))[l];
        float2 v1 = ((const float2*)(h0 + (size_t)e1.x * HDIM))[l];
        acc.x = fmaf(v0.x, w0, acc.x); acc.y = fmaf(v0.y, w0, acc.y);
        acc.x = fmaf(v1.x, w1, acc.x); acc.y = fmaf(v1.y, w1, acc.y);
    }
    if (j < end) {
        int2 e0 = bucket[j];
        float w0 = __int_as_float(e0.y);
        float2 v0 = ((const float2*)(h0 + (size_t)e0.x * HDIM))[l];
        acc.x = fmaf(v0.x, w0, acc.x); acc.y = fmaf(v0.y, w0, acc.y);
    }
    ((float2*)(msg + (size_t)n * HDIM))[l] = acc;
}

// ---------------------------------------------------------------- k3: h = relu(h0 + msg@W_msg); per-graph mean
__global__ __launch_bounds__(256) void k3_msg_relu_pool(const float* __restrict__ h0,
                                                        const float* __restrict__ msg,
                                                        const float* __restrict__ Wmsg,
                                                        const int* __restrict__ batch,
                                                        float* __restrict__ gmean, int N) {
    int g = blockIdx.x;
    int t = threadIdx.x;
    int col = t & (HDIM - 1);
    int half = t >> 7;

    int lo = 0, hi = N;
    while (lo < hi) { int m = (lo + hi) >> 1; if (batch[m] < g) lo = m + 1; else hi = m; }
    int start = lo;
    hi = N;
    while (lo < hi) { int m = (lo + hi) >> 1; if (batch[m] < g + 1) lo = m + 1; else hi = m; }
    int end = lo;

    float wc[HDIM];
#pragma unroll
    for (int k = 0; k < HDIM; ++k) wc[k] = Wmsg[k * HDIM + col];

    __shared__ __align__(16) float mrow[2][HDIM];
    __shared__ float red[HDIM];

    float accp = 0.f;
    for (int n0 = start; n0 < end; n0 += 2) {
        int nn = n0 + half;
        if (nn < end) mrow[half][col] = msg[(size_t)nn * HDIM + col];
        __syncthreads();
        if (nn < end) {
            const float4* m4 = (const float4*)mrow[half];
            float a0 = 0.f, a1 = 0.f, a2 = 0.f, a3 = 0.f;
#pragma unroll
            for (int q = 0; q < HDIM / 4; ++q) {
                float4 mv = m4[q];
                a0 = fmaf(mv.x, wc[4 * q + 0], a0);
                a1 = fmaf(mv.y, wc[4 * q + 1], a1);
                a2 = fmaf(mv.z, wc[4 * q + 2], a2);
                a3 = fmaf(mv.w, wc[4 * q + 3], a3);
            }
            float hv = h0[(size_t)nn * HDIM + col] + ((a0 + a1) + (a2 + a3));
            accp += fmaxf(hv, 0.f);
        }
        __syncthreads();
    }

    if (half == 0) red[col] = accp;
    __syncthreads();
    if (half == 1) red[col] += accp;
    __syncthreads();
    if (t < HDIM) {
        int cnt = end - start;
        gmean[(size_t)g * HDIM + t] = (cnt > 0) ? red[t] / (float)cnt : 0.f;
    }
}

// ---------------------------------------------------------------- k4: backbone + heads
__global__ __launch_bounds__(256) void k4_heads(const float* __restrict__ gmean,
                                                const float* __restrict__ W1,
                                                const float* __restrict__ W2,
                                                const float* __restrict__ Wa,
                                                const float* __restrict__ Ws,
                                                const float* __restrict__ Wt,
                                                const float* __restrict__ Wact,
                                                const float* __restrict__ Wv1,
                                                const float* __restrict__ Wv2,
                                                float* __restrict__ out) {
    int g = blockIdx.x;
    int t = threadIdx.x;
    __shared__ float gv[HDIM];
    __shared__ float s1[HDIM];
    __shared__ float s2v[64];
    __shared__ float v1[32];

    if (t < HDIM) gv[t] = gmean[(size_t)g * HDIM + t];
    __syncthreads();

    if (t < HDIM) {
        float s = 0.f;
#pragma unroll 8
        for (int k = 0; k < HDIM; ++k)
            s = fmaf(gv[k], W1[k * HDIM + t] + W1[(k + HDIM) * HDIM + t], s);
        s1[t] = fmaxf(s, 0.f);
    }
    __syncthreads();

    if (t < 64) {
        float s = 0.f;
#pragma unroll 8
        for (int k = 0; k < HDIM; ++k)
            s = fmaf(s1[k], W2[k * 64 + t], s);
        s2v[t] = fmaxf(s, 0.f);
    }
    __syncthreads();

    for (int c = t; c < 2009; c += 256) {
        const float* W; int colc, ncol; size_t oidx;
        if (c < 5)        { W = Wa;   colc = c;        ncol = 5;    oidx = (size_t)g * 5 + colc; }
        else if (c < 1005){ W = Ws;   colc = c - 5;    ncol = 1000; oidx = 2560 + (size_t)g * 1000 + colc; }
        else if (c < 2005){ W = Wt;   colc = c - 1005; ncol = 1000; oidx = 514560 + (size_t)g * 1000 + colc; }
        else              { W = Wact; colc = c - 2005; ncol = 4;    oidx = 1026560 + (size_t)g * 4 + colc; }
        float acc = 0.f;
#pragma unroll 8
        for (int k = 0; k < 64; ++k)
            acc = fmaf(s2v[k], W[k * ncol + colc], acc);
        out[oidx] = acc;
    }

    if (t < 32) {
        float s = 0.f;
#pragma unroll 8
        for (int k = 0; k < 64; ++k)
            s = fmaf(s2v[k], Wv1[k * 32 + t], s);
        v1[t] = fmaxf(s, 0.f);
    }
    __syncthreads();
    if (t == 0) {
        float s = 0.f;
#pragma unroll
        for (int k = 0; k < 32; ++k)
            s = fmaf(v1[k], Wv2[k], s);
        out[1028608 + (size_t)g] = tanhf(s);
    }
}

// ----------------------------------------------------------------
extern "C" void kernel_launch(void* const* d_in, const int* in_sizes, int n_in,
                              void* d_out, int out_size, void* d_ws, size_t ws_size,
                              hipStream_t stream) {
    const float* x     = (const float*)d_in[0];
    const int*   ei    = (const int*)d_in[1];
    const float* ew    = (const float*)d_in[2];
    const int*   batch = (const int*)d_in[4];
    const float* Win   = (const float*)d_in[6];
    const float* Wmsg  = (const float*)d_in[7];
    const float* W1    = (const float*)d_in[8];
    const float* W2    = (const float*)d_in[9];
    const float* Wa    = (const float*)d_in[10];
    const float* Ws    = (const float*)d_in[11];
    const float* Wt    = (const float*)d_in[12];
    const float* Wact  = (const float*)d_in[13];
    const float* Wv1   = (const float*)d_in[14];
    const float* Wv2   = (const float*)d_in[15];
    float* out = (float*)d_out;

    char* ws = (char*)d_ws;
    const size_t nh_bytes = (size_t)NODES * HDIM * sizeof(float);   // 64 MB
    float* h0     = (float*)(ws);
    float* msg    = (float*)(ws + nh_bytes);
    float* gmean  = (float*)(ws + 2 * nh_bytes);
    char*  p      = ws + 2 * nh_bytes + (size_t)NGRAPH * HDIM * sizeof(float);
    int*   count  = (int*)(p);                 p += (size_t)NODES * 4;
    int*   offs   = (int*)(p);                 p += (size_t)NODES * 4;
    int*   cursor = (int*)(p);                 p += (size_t)NODES * 4;
    int*   bsums  = (int*)(p);                 p += 256 * 4;
    int*   bbase  = (int*)(p);                 p += 256 * 4;
    int2*  bucket = (int2*)(p);                p += (size_t)EDGES * 8;

    // CSR build (independent of h0)
    hipMemsetAsync(count, 0, (size_t)NODES * 4, stream);
    kh_hist <<<EDGES / 256, 256, 0, stream>>>(ei, count, EDGES);
    kh_scanA<<<256, 256, 0, stream>>>(count, offs, bsums);
    kh_scanB<<<1, 256, 0, stream>>>(bsums, bbase);
    kh_scanC<<<256, 256, 0, stream>>>(offs, cursor, bbase);
    kh_fill <<<EDGES / 256, 256, 0, stream>>>(ei, ew, cursor, bucket, EDGES);

    // node projection
    k1_proj<<<2048, 256, 0, stream>>>(x, Win, h0, NODES);

    // gather-side message reduction (no float atomics, no msg memset)
    kg_gather<<<(NODES * 64) / 256, 256, 0, stream>>>(h0, offs, cursor, bucket, msg, NODES);

    k3_msg_relu_pool<<<NGRAPH, 256, 0, stream>>>(h0, msg, Wmsg, batch, gmean, NODES);

    k4_heads<<<NGRAPH, 256, 0, stream>>>(gmean, W1, W2, Wa, Ws, Wt, Wact, Wv1, Wv2, out);
}

// Round 3
// 422.618 us; speedup vs baseline: 2.7056x; 1.1433x over previous
//
#include <hip/hip_runtime.h>
#include <math.h>

#define NODES   131072
#define EDGES   1048576
#define FDIM    32
#define HDIM    128
#define NGRAPH  512

typedef __attribute__((ext_vector_type(8))) short short8v;
typedef __attribute__((ext_vector_type(4))) float float4v;

__device__ __forceinline__ unsigned short f2bf(float f) {
    union { float f; unsigned int u; } v; v.f = f;
    unsigned int u = v.u;
    unsigned int r = (u + 0x7fffu + ((u >> 16) & 1u)) >> 16;   // RNE
    return (unsigned short)r;
}

// ---------------------------------------------------------------- k1: h0 = X @ W_in
__global__ __launch_bounds__(256) void k1_proj(const float* __restrict__ x,
                                               const float* __restrict__ Win,
                                               float* __restrict__ h0, int N) {
    int t = threadIdx.x;
    int col = t & (HDIM - 1);
    int group0 = (int)((blockIdx.x * (size_t)blockDim.x + t) >> 7);
    int stride = (int)((gridDim.x * (size_t)blockDim.x) >> 7);
    for (int n = group0; n < N; n += stride) {
        const float* xr = x + (size_t)n * FDIM;
        float s = 0.f;
#pragma unroll
        for (int f = 0; f < FDIM; ++f)
            s = fmaf(xr[f], Win[f * HDIM + col], s);
        h0[(size_t)n * HDIM + col] = s;
    }
}

// ---------------------------------------------------------------- CSR build (counting sort by target)
__global__ __launch_bounds__(256) void kh_hist(const int* __restrict__ ei,
                                               int* __restrict__ count, int E) {
    int e = blockIdx.x * blockDim.x + threadIdx.x;
    if (e < E) atomicAdd(&count[ei[E + e]], 1);
}

__global__ __launch_bounds__(256) void kh_scanA(const int* __restrict__ count,
                                                int* __restrict__ offs,
                                                int* __restrict__ blockSums) {
    int b = blockIdx.x, t = threadIdx.x;
    int base = b * 512 + 2 * t;
    int a0 = count[base], a1 = count[base + 1];
    int pair = a0 + a1;
    __shared__ int sh[256];
    sh[t] = pair;
    __syncthreads();
    for (int off = 1; off < 256; off <<= 1) {
        int v = (t >= off) ? sh[t - off] : 0;
        __syncthreads();
        sh[t] += v;
        __syncthreads();
    }
    int excl = sh[t] - pair;
    offs[base] = excl;
    offs[base + 1] = excl + a0;
    if (t == 255) blockSums[b] = sh[255];
}

__global__ __launch_bounds__(256) void kh_scanB(const int* __restrict__ blockSums,
                                                int* __restrict__ blockBase) {
    int t = threadIdx.x;
    int v0 = blockSums[t];
    __shared__ int sh[256];
    sh[t] = v0;
    __syncthreads();
    for (int off = 1; off < 256; off <<= 1) {
        int v = (t >= off) ? sh[t - off] : 0;
        __syncthreads();
        sh[t] += v;
        __syncthreads();
    }
    blockBase[t] = sh[t] - v0;
}

__global__ __launch_bounds__(256) void kh_scanC(int* __restrict__ offs,
                                                int* __restrict__ cursor,
                                                const int* __restrict__ blockBase) {
    int b = blockIdx.x, t = threadIdx.x;
    int base = b * 512 + 2 * t;
    int add = blockBase[b];
    int o0 = offs[base] + add, o1 = offs[base + 1] + add;
    offs[base] = o0; offs[base + 1] = o1;
    cursor[base] = o0; cursor[base + 1] = o1;
}

__global__ __launch_bounds__(256) void kh_fill(const int* __restrict__ ei,
                                               const float* __restrict__ ew,
                                               int* __restrict__ cursor,
                                               int2* __restrict__ bucket, int E) {
    int e = blockIdx.x * blockDim.x + threadIdx.x;
    if (e >= E) return;
    int src = ei[e];
    int tgt = ei[E + e];
    float w = ew[e];
    int pos = atomicAdd(&cursor[tgt], 1);
    bucket[pos] = make_int2(src, __float_as_int(w));
}

// ---------------------------------------------------------------- gather: msgb[n] = bf16( sum_in h0[src]*w )
__global__ __launch_bounds__(256) void kg_gather(const float* __restrict__ h0,
                                                 const int* __restrict__ offs,
                                                 const int* __restrict__ cursor,
                                                 const int2* __restrict__ bucket,
                                                 unsigned short* __restrict__ msgb, int N) {
    long long gid = blockIdx.x * (long long)blockDim.x + threadIdx.x;
    int n = (int)(gid >> 6);
    if (n >= N) return;
    int l = (int)(gid & 63);
    int beg = offs[n];
    int end = cursor[n];
    float2 acc = {0.f, 0.f};
    int j = beg;
    for (; j + 1 < end; j += 2) {
        int2 e0 = bucket[j];
        int2 e1 = bucket[j + 1];
        float w0 = __int_as_float(e0.y);
        float w1 = __int_as_float(e1.y);
        float2 v0 = ((const float2*)(h0 + (size_t)e0.x * HDIM))[l];
        float2 v1 = ((const float2*)(h0 + (size_t)e1.x * HDIM))[l];
        acc.x = fmaf(v0.x, w0, acc.x); acc.y = fmaf(v0.y, w0, acc.y);
        acc.x = fmaf(v1.x, w1, acc.x); acc.y = fmaf(v1.y, w1, acc.y);
    }
    if (j < end) {
        int2 e0 = bucket[j];
        float w0 = __int_as_float(e0.y);
        float2 v0 = ((const float2*)(h0 + (size_t)e0.x * HDIM))[l];
        acc.x = fmaf(v0.x, w0, acc.x); acc.y = fmaf(v0.y, w0, acc.y);
    }
    ushort2 o; o.x = f2bf(acc.x); o.y = f2bf(acc.y);
    ((ushort2*)(msgb + (size_t)n * HDIM))[l] = o;
}

// ---------------------------------------------------------------- prep: frag-ordered bf16 W_msg
// wfrag[((c*4+kk)*64 + l)] = 8 bf16: B[k0..k0+7][c*16 + (l&15)], k0 = kk*32 + (l>>4)*8
__global__ __launch_bounds__(256) void kp_wfrag(const float* __restrict__ Wmsg,
                                                unsigned short* __restrict__ wfrag) {
    int flat = blockIdx.x * 256 + threadIdx.x;      // 0..2047
    int l = flat & 63;
    int fragid = flat >> 6;                         // 0..31
    int c = fragid >> 2, kk = fragid & 3;
    int col = c * 16 + (l & 15);
    int k0 = kk * 32 + (l >> 4) * 8;
    unsigned short tmp[8];
#pragma unroll
    for (int j = 0; j < 8; ++j)
        tmp[j] = f2bf(Wmsg[(k0 + j) * HDIM + col]);
    short8v v;
#pragma unroll
    for (int j = 0; j < 8; ++j) v[j] = (short)tmp[j];
    ((short8v*)wfrag)[flat] = v;
}

// ---------------------------------------------------------------- counts per graph
__global__ void kc_cnt(const int* __restrict__ batch, int* __restrict__ cnt, int N) {
    int g = blockIdx.x * blockDim.x + threadIdx.x;
    if (g >= NGRAPH) return;
    int lo = 0, hi = N;
    while (lo < hi) { int m = (lo + hi) >> 1; if (batch[m] < g) lo = m + 1; else hi = m; }
    int start = lo;
    hi = N;
    while (lo < hi) { int m = (lo + hi) >> 1; if (batch[m] < g + 1) lo = m + 1; else hi = m; }
    cnt[g] = lo - start;
}

// ---------------------------------------------------------------- k3a: MFMA GEMM + relu + fused segmented pool
// Block = 4 waves, 64 nodes. Wave w: 16-node strip, full 128 cols.
// B held entirely in VGPRs (32 frags, loaded coalesced from frag-ordered wfrag).
__global__ __launch_bounds__(256, 2) void k3a_mfma_pool(const unsigned short* __restrict__ msgb,
                                                        const float* __restrict__ h0,
                                                        const unsigned short* __restrict__ wfrag,
                                                        const int* __restrict__ batch,
                                                        float* __restrict__ gsum, int N) {
    int t = threadIdx.x;
    int wid = t >> 6, l = t & 63;
    int block_base = blockIdx.x * 64;
    int strip = block_base + wid * 16;

    __shared__ float pool[8][HDIM];

    // B fragments: 32 x short8v = 128 VGPRs
    const short8v* wf = (const short8v*)wfrag;
    short8v bf[8][4];
#pragma unroll
    for (int c = 0; c < 8; ++c)
#pragma unroll
        for (int kk = 0; kk < 4; ++kk)
            bf[c][kk] = wf[(c * 4 + kk) * 64 + l];

    // A fragments: row = strip + (l&15), 16B chunk kk*4 + (l>>4)
    const short8v* mrow = (const short8v*)(msgb + (size_t)(strip + (l & 15)) * HDIM);
    short8v af[4];
#pragma unroll
    for (int kk = 0; kk < 4; ++kk)
        af[kk] = mrow[kk * 4 + (l >> 4)];

    float4v acc[8];
#pragma unroll
    for (int c = 0; c < 8; ++c) acc[c] = (float4v){0.f, 0.f, 0.f, 0.f};

#pragma unroll
    for (int kk = 0; kk < 4; ++kk)
#pragma unroll
        for (int c = 0; c < 8; ++c)
            acc[c] = __builtin_amdgcn_mfma_f32_16x16x32_bf16(af[kk], bf[c][kk], acc[c], 0, 0, 0);

    // epilogue: h = relu(h0 + acc), segmented pool into gsum
    int bfirst = batch[block_base];
    int blast  = batch[block_base + 63];
    int span = blast - bfirst + 1;
    int rbase = strip + (l >> 4) * 4;     // C/D: col = lane&15, row = (lane>>4)*4 + reg
    int col = l & 15;

    if (span <= 8) {
        for (int i = t; i < 8 * HDIM; i += 256) ((float*)pool)[i] = 0.f;
        __syncthreads();
#pragma unroll
        for (int r = 0; r < 4; ++r) {
            int row = rbase + r;
            int g = batch[row] - bfirst;
#pragma unroll
            for (int c = 0; c < 8; ++c) {
                float hv = fmaxf(h0[(size_t)row * HDIM + c * 16 + col] + acc[c][r], 0.f);
                atomicAdd(&pool[g][c * 16 + col], hv);
            }
        }
        __syncthreads();
        int cc = t & 127;
        for (int s = t >> 7; s < span; s += 2) {
            float v = pool[s][cc];
            if (v != 0.f) atomicAdd(&gsum[(size_t)(bfirst + s) * HDIM + cc], v);
        }
    } else {
        // rare fallback: tiny graphs — direct global atomics
#pragma unroll
        for (int r = 0; r < 4; ++r) {
            int row = rbase + r;
            int g = batch[row];
#pragma unroll
            for (int c = 0; c < 8; ++c) {
                float hv = fmaxf(h0[(size_t)row * HDIM + c * 16 + col] + acc[c][r], 0.f);
                atomicAdd(&gsum[(size_t)g * HDIM + c * 16 + col], hv);
            }
        }
    }
}

// ---------------------------------------------------------------- k4: backbone + heads (divide-at-load)
__global__ __launch_bounds__(256) void k4_heads(const float* __restrict__ gsum,
                                                const int* __restrict__ cnt,
                                                const float* __restrict__ W1,
                                                const float* __restrict__ W2,
                                                const float* __restrict__ Wa,
                                                const float* __restrict__ Ws,
                                                const float* __restrict__ Wt,
                                                const float* __restrict__ Wact,
                                                const float* __restrict__ Wv1,
                                                const float* __restrict__ Wv2,
                                                float* __restrict__ out) {
    int g = blockIdx.x;
    int t = threadIdx.x;
    __shared__ float gv[HDIM];
    __shared__ float s1[HDIM];
    __shared__ float s2v[64];
    __shared__ float v1[32];

    if (t < HDIM) {
        int c = cnt[g];
        gv[t] = (c > 0) ? gsum[(size_t)g * HDIM + t] / (float)c : 0.f;
    }
    __syncthreads();

    if (t < HDIM) {
        float s = 0.f;
#pragma unroll 8
        for (int k = 0; k < HDIM; ++k)
            s = fmaf(gv[k], W1[k * HDIM + t] + W1[(k + HDIM) * HDIM + t], s);
        s1[t] = fmaxf(s, 0.f);
    }
    __syncthreads();

    if (t < 64) {
        float s = 0.f;
#pragma unroll 8
        for (int k = 0; k < HDIM; ++k)
            s = fmaf(s1[k], W2[k * 64 + t], s);
        s2v[t] = fmaxf(s, 0.f);
    }
    __syncthreads();

    for (int c = t; c < 2009; c += 256) {
        const float* W; int colc, ncol; size_t oidx;
        if (c < 5)        { W = Wa;   colc = c;        ncol = 5;    oidx = (size_t)g * 5 + colc; }
        else if (c < 1005){ W = Ws;   colc = c - 5;    ncol = 1000; oidx = 2560 + (size_t)g * 1000 + colc; }
        else if (c < 2005){ W = Wt;   colc = c - 1005; ncol = 1000; oidx = 514560 + (size_t)g * 1000 + colc; }
        else              { W = Wact; colc = c - 2005; ncol = 4;    oidx = 1026560 + (size_t)g * 4 + colc; }
        float acc = 0.f;
#pragma unroll 8
        for (int k = 0; k < 64; ++k)
            acc = fmaf(s2v[k], W[k * ncol + colc], acc);
        out[oidx] = acc;
    }

    if (t < 32) {
        float s = 0.f;
#pragma unroll 8
        for (int k = 0; k < 64; ++k)
            s = fmaf(s2v[k], Wv1[k * 32 + t], s);
        v1[t] = fmaxf(s, 0.f);
    }
    __syncthreads();
    if (t == 0) {
        float s = 0.f;
#pragma unroll
        for (int k = 0; k < 32; ++k)
            s = fmaf(v1[k], Wv2[k], s);
        out[1028608 + (size_t)g] = tanhf(s);
    }
}

// ----------------------------------------------------------------
extern "C" void kernel_launch(void* const* d_in, const int* in_sizes, int n_in,
                              void* d_out, int out_size, void* d_ws, size_t ws_size,
                              hipStream_t stream) {
    const float* x     = (const float*)d_in[0];
    const int*   ei    = (const int*)d_in[1];
    const float* ew    = (const float*)d_in[2];
    const int*   batch = (const int*)d_in[4];
    const float* Win   = (const float*)d_in[6];
    const float* Wmsg  = (const float*)d_in[7];
    const float* W1    = (const float*)d_in[8];
    const float* W2    = (const float*)d_in[9];
    const float* Wa    = (const float*)d_in[10];
    const float* Ws    = (const float*)d_in[11];
    const float* Wt    = (const float*)d_in[12];
    const float* Wact  = (const float*)d_in[13];
    const float* Wv1   = (const float*)d_in[14];
    const float* Wv2   = (const float*)d_in[15];
    float* out = (float*)d_out;

    char* ws = (char*)d_ws;
    const size_t nh_bytes = (size_t)NODES * HDIM * sizeof(float);         // 64 MB
    float*          h0     = (float*)(ws);
    unsigned short* msgb   = (unsigned short*)(ws + nh_bytes);            // 32 MB
    char*           p      = ws + nh_bytes + (size_t)NODES * HDIM * 2;
    float*          gsum   = (float*)(p);      p += (size_t)NGRAPH * HDIM * 4;
    int*            cnt    = (int*)(p);        p += (size_t)NGRAPH * 4;
    unsigned short* wfrag  = (unsigned short*)(p); p += 32 * 64 * 16;
    int*            count  = (int*)(p);        p += (size_t)NODES * 4;
    int*            offs   = (int*)(p);        p += (size_t)NODES * 4;
    int*            cursor = (int*)(p);        p += (size_t)NODES * 4;
    int*            bsums  = (int*)(p);        p += 256 * 4;
    int*            bbase  = (int*)(p);        p += 256 * 4;
    int2*           bucket = (int2*)(p);       p += (size_t)EDGES * 8;

    hipMemsetAsync(count, 0, (size_t)NODES * 4, stream);
    hipMemsetAsync(gsum, 0, (size_t)NGRAPH * HDIM * 4, stream);

    // CSR build
    kh_hist <<<EDGES / 256, 256, 0, stream>>>(ei, count, EDGES);
    kh_scanA<<<256, 256, 0, stream>>>(count, offs, bsums);
    kh_scanB<<<1, 256, 0, stream>>>(bsums, bbase);
    kh_scanC<<<256, 256, 0, stream>>>(offs, cursor, bbase);
    kh_fill <<<EDGES / 256, 256, 0, stream>>>(ei, ew, cursor, bucket, EDGES);

    // independent prep
    k1_proj <<<2048, 256, 0, stream>>>(x, Win, h0, NODES);
    kp_wfrag<<<8, 256, 0, stream>>>(Wmsg, wfrag);
    kc_cnt  <<<2, 256, 0, stream>>>(batch, cnt, NODES);

    // message gather (bf16 out)
    kg_gather<<<(NODES * 64) / 256, 256, 0, stream>>>(h0, offs, cursor, bucket, msgb, NODES);

    // MFMA GEMM + relu + fused pool
    k3a_mfma_pool<<<NODES / 64, 256, 0, stream>>>(msgb, h0, wfrag, batch, gsum, NODES);

    k4_heads<<<NGRAPH, 256, 0, stream>>>(gsum, cnt, W1, W2, Wa, Ws, Wt, Wact, Wv1, Wv2, out);
}